// Round 1
// baseline (209.960 us; speedup 1.0000x reference)
//
#include <hip/hip_runtime.h>
#include <hip/hip_bf16.h>
#include <cstdint>

#define BS    16
#define NA    33600
#define NMAX  64
#define NC    80
#define TOPKN 13
#define EPSF  1e-9f

// ---- output layout (float32, concatenated flat in return order) ----
// target_labels: BS*NA            @ 0
// target_bboxes: BS*NA*3          @ 537600
// target_scores: BS*NA*NC         @ 2150400
// fg_mask:       BS*NA            @ 45158400
// target_gt_idx: BS*NA            @ 45696000
#define O_LAB 0
#define O_BOX 537600
#define O_SCR 2150400
#define O_FG  45158400
#define O_GT  45696000

// ---- workspace layout (bytes) ----
// topk  : 1024*13*4  = 53248       @ 0
// counts: 537600*4   = 2150400     @ 53248
// jsum  : 537600*4                 @ 2203648
// tgt   : 537600*4                 @ 4354048
// am    : 537600*4                 @ 6504448
// pos_align: 1024*4                @ 8654848
// pos_over : 1024*4                @ 8658944
// total: 8663040 bytes

// ============================================================
// K1: per (b,j) row: compute align_metric over anchors, exact top-13
// ============================================================
__global__ __launch_bounds__(256) void k_topk(
    const float* __restrict__ pd_scores,   // [BS,NA,NC]
    const float* __restrict__ pd_circles,  // [BS,NA,3]
    const float* __restrict__ anc,         // [NA,2]
    const int*   __restrict__ gt_labels,   // [BS,NMAX]
    const float* __restrict__ gt_bboxes,   // [BS,NMAX,3]
    const float* __restrict__ mask_gt,     // [BS,NMAX]
    int*         __restrict__ topk_out)    // [BS*NMAX,13]
{
    const int row = blockIdx.x;            // b*NMAX + j
    const int tid = threadIdx.x;

    __shared__ float sv[256 * TOPKN];
    __shared__ int   si[256 * TOPKN];
    __shared__ float rv[256];
    __shared__ int   ri[256];
    __shared__ int   win_i[TOPKN];
    __shared__ float win_v0;

    if (mask_gt[row] <= 0.f) {
        if (tid < TOPKN) topk_out[row * TOPKN + tid] = -1;
        return;
    }

    const float gx = gt_bboxes[row * 3 + 0];
    const float gy = gt_bboxes[row * 3 + 1];
    const float gr = gt_bboxes[row * 3 + 2];
    const int   lbl = gt_labels[row];
    const int   b   = row >> 6;
    const float* __restrict__ ps = pd_scores + (size_t)b * NA * NC + lbl;
    const float* __restrict__ pc = pd_circles + (size_t)b * NA * 3;
    const float2* __restrict__ anc2 = (const float2*)anc;

    // per-thread sorted top-13 (value desc, anchor idx asc on ties)
    float tv[TOPKN]; int ti[TOPKN];
#pragma unroll
    for (int k = 0; k < TOPKN; ++k) { tv[k] = -1.f; ti[k] = 0x7fffffff; }

    for (int a = tid; a < NA; a += 256) {
        float2 ap = anc2[a];
        float dx = gx - ap.x, dy = gy - ap.y;
        float m = 0.f;
        if (sqrtf(dx * dx + dy * dy) <= gr) {
            float px = pc[a * 3 + 0], py = pc[a * 3 + 1], pr = pc[a * 3 + 2];
            float ddx = gx - px, ddy = gy - py;
            float d  = sqrtf(ddx * ddx + ddy * ddy);
            float rs = gr + pr;
            float iou = fmaxf((rs - d) / rs, 0.f);
            float i2 = iou * iou;
            m = ps[(size_t)a * NC] * (i2 * i2 * i2);
        }
        if (m > tv[TOPKN - 1]) {
            // static-index unrolled insertion (desc, stable: equal keeps earlier idx first)
#pragma unroll
            for (int p = TOPKN - 1; p > 0; --p) {
                if (tv[p] < m) {
                    bool here = (tv[p - 1] >= m);
                    tv[p] = here ? m : tv[p - 1];
                    ti[p] = here ? a : ti[p - 1];
                }
            }
            if (tv[0] < m) { tv[0] = m; ti[0] = a; }
        }
    }

#pragma unroll
    for (int k = 0; k < TOPKN; ++k) { sv[tid * TOPKN + k] = tv[k]; si[tid * TOPKN + k] = ti[k]; }
    __syncthreads();

    // 13 exact selection passes over 256*13 candidates
    for (int k = 0; k < TOPKN; ++k) {
        float bv = -2.f; int bi = 0x7fffffff;
#pragma unroll
        for (int e = 0; e < TOPKN; ++e) {
            float v = sv[tid * TOPKN + e]; int ii = si[tid * TOPKN + e];
            if (v > bv || (v == bv && ii < bi)) { bv = v; bi = ii; }
        }
        rv[tid] = bv; ri[tid] = bi;
        __syncthreads();
        for (int s = 128; s > 0; s >>= 1) {
            if (tid < s) {
                float v2 = rv[tid + s]; int i2 = ri[tid + s];
                if (v2 > rv[tid] || (v2 == rv[tid] && i2 < ri[tid])) { rv[tid] = v2; ri[tid] = i2; }
            }
            __syncthreads();
        }
        int wi = ri[0]; float wv = rv[0];
        if (tid == 0) { win_i[k] = wi; if (k == 0) win_v0 = wv; }
        // owner thread removes the winner from its candidate list
        if ((wi & 255) == tid) {
#pragma unroll
            for (int e = 0; e < TOPKN; ++e)
                if (si[tid * TOPKN + e] == wi) sv[tid * TOPKN + e] = -2.f;
        }
        __syncthreads();
    }

    if (tid < TOPKN) {
        bool ok = win_v0 > EPSF;   // topk_mask: max(topk_metrics) > EPS
        topk_out[row * TOPKN + tid] = ok ? win_i[tid] : -1;
    }
}

// ============================================================
// K2: scatter claims (mask_pos before multi-resolution)
// ============================================================
__global__ __launch_bounds__(256) void k_claims(
    const float* __restrict__ anc,
    const float* __restrict__ gt_bboxes,
    const int*   __restrict__ topk,
    int*         __restrict__ counts,
    int*         __restrict__ jsum)
{
    int t = blockIdx.x * 256 + threadIdx.x;
    if (t >= BS * NMAX * TOPKN) return;
    int r = t / TOPKN;
    int a = topk[t];
    if (a < 0) return;
    int b = r >> 6, j = r & 63;
    float gx = gt_bboxes[r * 3 + 0], gy = gt_bboxes[r * 3 + 1], gr = gt_bboxes[r * 3 + 2];
    float dx = gx - anc[a * 2 + 0], dy = gy - anc[a * 2 + 1];
    if (sqrtf(dx * dx + dy * dy) <= gr) {     // mask_in_gts (mask_gt already 1 for live rows)
        atomicAdd(counts + b * NA + a, 1);
        atomicAdd(jsum + b * NA + a, j);
    }
}

// ============================================================
// K3: resolve multi-claim anchors, per-row pos_align/pos_over
// ============================================================
__global__ __launch_bounds__(256) void k_resolve(
    const float* __restrict__ pd_scores,
    const float* __restrict__ pd_circles,
    const float* __restrict__ anc,
    const int*   __restrict__ gt_labels,
    const float* __restrict__ gt_bboxes,
    const float* __restrict__ mask_gt,
    const int*   __restrict__ counts,
    const int*   __restrict__ jsum,
    int*         __restrict__ tgt_ws,
    float*       __restrict__ am_ws,
    unsigned*    __restrict__ pos_align,
    unsigned*    __restrict__ pos_over)
{
    int i = blockIdx.x * 256 + threadIdx.x;   // < BS*NA
    int b = i / NA, a = i - b * NA;
    int cnt = counts[i];
    float ax = anc[a * 2 + 0], ay = anc[a * 2 + 1];

    int tgt = -1;
    if (cnt == 1) {
        tgt = jsum[i];
    } else if (cnt > 1) {
        // argmax_j overlaps[b,j,a]  (masked IoU, first occurrence on ties)
        float px = pd_circles[((size_t)b * NA + a) * 3 + 0];
        float py = pd_circles[((size_t)b * NA + a) * 3 + 1];
        float pr = pd_circles[((size_t)b * NA + a) * 3 + 2];
        float best = -1.f; int bj = 0;
        for (int j = 0; j < NMAX; ++j) {
            int row = b * NMAX + j;
            float ov = 0.f;
            if (mask_gt[row] > 0.f) {
                float gx = gt_bboxes[row * 3 + 0], gy = gt_bboxes[row * 3 + 1], gr = gt_bboxes[row * 3 + 2];
                float dx = gx - ax, dy = gy - ay;
                if (sqrtf(dx * dx + dy * dy) <= gr) {
                    float ddx = gx - px, ddy = gy - py;
                    float d  = sqrtf(ddx * ddx + ddy * ddy);
                    float rs = gr + pr;
                    ov = fmaxf((rs - d) / rs, 0.f);
                }
            }
            if (ov > best) { best = ov; bj = j; }
        }
        tgt = bj;
    }
    tgt_ws[i] = tgt;

    float am = 0.f, ovv = 0.f;
    if (tgt >= 0) {
        int row = b * NMAX + tgt;
        if (mask_gt[row] > 0.f) {
            float gx = gt_bboxes[row * 3 + 0], gy = gt_bboxes[row * 3 + 1], gr = gt_bboxes[row * 3 + 2];
            float dx = gx - ax, dy = gy - ay;
            if (sqrtf(dx * dx + dy * dy) <= gr) {
                float px = pd_circles[((size_t)b * NA + a) * 3 + 0];
                float py = pd_circles[((size_t)b * NA + a) * 3 + 1];
                float pr = pd_circles[((size_t)b * NA + a) * 3 + 2];
                float ddx = gx - px, ddy = gy - py;
                float d  = sqrtf(ddx * ddx + ddy * ddy);
                float rs = gr + pr;
                float iou = fmaxf((rs - d) / rs, 0.f);
                float i2 = iou * iou;
                float s  = pd_scores[((size_t)b * NA + a) * NC + gt_labels[row]];
                am  = s * (i2 * i2 * i2);
                ovv = iou;
            }
        }
        atomicMax(pos_align + row, __float_as_uint(am));
        atomicMax(pos_over  + row, __float_as_uint(ovv));
    }
    am_ws[i] = am;
}

// ============================================================
// K4: write the 5 outputs
// ============================================================
__global__ __launch_bounds__(256) void k_write(
    const int*      __restrict__ gt_labels,
    const float*    __restrict__ gt_bboxes,
    const int*      __restrict__ tgt_ws,
    const float*    __restrict__ am_ws,
    const unsigned* __restrict__ pos_align,
    const unsigned* __restrict__ pos_over,
    float*          __restrict__ out)
{
    int i = blockIdx.x * 256 + threadIdx.x;   // < BS*NA
    int b = i / NA;
    int tgt = tgt_ws[i];
    bool fg = (tgt >= 0);
    int jj  = fg ? tgt : 0;
    int row = b * NMAX + jj;

    int lbl = max(gt_labels[row], 0);
    out[O_LAB + i] = (float)lbl;
    out[O_BOX + (size_t)i * 3 + 0] = gt_bboxes[row * 3 + 0];
    out[O_BOX + (size_t)i * 3 + 1] = gt_bboxes[row * 3 + 1];
    out[O_BOX + (size_t)i * 3 + 2] = gt_bboxes[row * 3 + 2];
    out[O_FG + i] = fg ? 1.f : 0.f;
    out[O_GT + i] = (float)jj;

    if (fg) {
        float pa = __uint_as_float(pos_align[row]);
        float po = __uint_as_float(pos_over[row]);
        float norm = am_ws[i] * po / (pa + EPSF);
        out[O_SCR + (size_t)i * NC + lbl] = norm;
    }
}

// ============================================================
extern "C" void kernel_launch(void* const* d_in, const int* in_sizes, int n_in,
                              void* d_out, int out_size, void* d_ws, size_t ws_size,
                              hipStream_t stream) {
    const float* pd_scores  = (const float*)d_in[0];
    const float* pd_circles = (const float*)d_in[1];
    const float* anc        = (const float*)d_in[2];
    const int*   gt_labels  = (const int*)d_in[3];
    const float* gt_bboxes  = (const float*)d_in[4];
    const float* mask_gt    = (const float*)d_in[5];
    float* out = (float*)d_out;

    char* ws = (char*)d_ws;
    int*      topk      = (int*)(ws + 0);
    int*      counts    = (int*)(ws + 53248);
    int*      jsum      = (int*)(ws + 2203648);
    int*      tgt_ws    = (int*)(ws + 4354048);
    float*    am_ws     = (float*)(ws + 6504448);
    unsigned* pos_align = (unsigned*)(ws + 8654848);
    unsigned* pos_over  = (unsigned*)(ws + 8658944);

    // zero: counts+jsum (contiguous), pos arrays (contiguous), scores output region
    hipMemsetAsync(counts, 0, 2 * 537600 * sizeof(int), stream);
    hipMemsetAsync(pos_align, 0, 2 * 1024 * sizeof(unsigned), stream);
    hipMemsetAsync(out + O_SCR, 0, (size_t)BS * NA * NC * sizeof(float), stream);

    k_topk<<<BS * NMAX, 256, 0, stream>>>(pd_scores, pd_circles, anc, gt_labels,
                                          gt_bboxes, mask_gt, topk);
    k_claims<<<(BS * NMAX * TOPKN + 255) / 256, 256, 0, stream>>>(anc, gt_bboxes, topk,
                                                                  counts, jsum);
    k_resolve<<<(BS * NA) / 256, 256, 0, stream>>>(pd_scores, pd_circles, anc, gt_labels,
                                                   gt_bboxes, mask_gt, counts, jsum,
                                                   tgt_ws, am_ws, pos_align, pos_over);
    k_write<<<(BS * NA) / 256, 256, 0, stream>>>(gt_labels, gt_bboxes, tgt_ws, am_ws,
                                                 pos_align, pos_over, out);
}

// Round 2
// 146.754 us; speedup vs baseline: 1.4307x; 1.4307x over previous
//
#include <hip/hip_runtime.h>
#include <hip/hip_bf16.h>
#include <cstdint>

#define BS    16
#define NA    33600
#define NMAX  64
#define NC    80
#define TOPKN 13
#define SEG   16
#define SEGLEN (NA / SEG)   // 2100
#define EPSF  1e-9f

// ---- output layout (float32, concatenated flat in return order) ----
#define O_LAB 0
#define O_BOX 537600
#define O_SCR 2150400
#define O_FG  45158400
#define O_GT  45696000

// ---- workspace layout (bytes) ----
// topk  : 1024*13*4  = 53248       @ 0
// REGION A (time-shared):
//   s1val: 1024*16*13*4 = 851968   @ 53248      (K1a..K1b only)
//   s1idx: 851968                  @ 905216
//   counts: 537600*4 = 2150400     @ 53248      (memset AFTER K1b)
//   jsum  : 537600*4               @ 2203648
// tgt   : 537600*4                 @ 4354048
// am    : 537600*4                 @ 6504448
// pos_align: 1024*4                @ 8654848
// pos_over : 1024*4                @ 8658944
// total: 8663040 bytes

// ============================================================
// K1a: per (row, segment): one wave scans SEGLEN anchors, outputs
// exact segment top-13 as (value, idx), tie-break (value desc, idx asc).
// ============================================================
__global__ __launch_bounds__(64) void k_topk_seg(
    const float* __restrict__ pd_scores,   // [BS,NA,NC]
    const float* __restrict__ pd_circles,  // [BS,NA,3]
    const float* __restrict__ anc,         // [NA,2]
    const int*   __restrict__ gt_labels,   // [BS,NMAX]
    const float* __restrict__ gt_bboxes,   // [BS,NMAX,3]
    const float* __restrict__ mask_gt,     // [BS,NMAX]
    float*       __restrict__ s1val,       // [1024*SEG, 13]
    int*         __restrict__ s1idx)
{
    const int blk  = blockIdx.x;        // row*SEG + seg
    const int row  = blk >> 4;
    const int seg  = blk & (SEG - 1);
    const int lane = threadIdx.x;

    float* outv = s1val + (size_t)blk * TOPKN;
    int*   outi = s1idx + (size_t)blk * TOPKN;

    if (mask_gt[row] <= 0.f) {
        if (lane < TOPKN) { outv[lane] = -2.f; outi[lane] = 0x7fffffff; }
        return;
    }

    const float gx = gt_bboxes[row * 3 + 0];
    const float gy = gt_bboxes[row * 3 + 1];
    const float gr = gt_bboxes[row * 3 + 2];
    const int   lbl = gt_labels[row];
    const int   b   = row >> 6;
    const float* __restrict__ ps = pd_scores + (size_t)b * NA * NC + lbl;
    const float* __restrict__ pc = pd_circles + (size_t)b * NA * 3;
    const float2* __restrict__ anc2 = (const float2*)anc;

    // per-lane sorted top-13 (value desc, anchor idx asc on ties)
    float tv[TOPKN]; int ti[TOPKN];
#pragma unroll
    for (int k = 0; k < TOPKN; ++k) { tv[k] = -1.f; ti[k] = 0x7fffffff; }

    const int base = seg * SEGLEN;
    for (int a = base + lane; a < base + SEGLEN; a += 64) {
        float2 ap = anc2[a];
        float dx = gx - ap.x, dy = gy - ap.y;
        float m = 0.f;
        if (sqrtf(dx * dx + dy * dy) <= gr) {
            float px = pc[a * 3 + 0], py = pc[a * 3 + 1], pr = pc[a * 3 + 2];
            float ddx = gx - px, ddy = gy - py;
            float d  = sqrtf(ddx * ddx + ddy * ddy);
            float rs = gr + pr;
            float iou = fmaxf((rs - d) / rs, 0.f);
            float i2 = iou * iou;
            m = ps[(size_t)a * NC] * (i2 * i2 * i2);
        }
        if (m > tv[TOPKN - 1]) {
            // static-index unrolled insertion (desc, stable: ties keep earlier idx first)
#pragma unroll
            for (int p = TOPKN - 1; p > 0; --p) {
                if (tv[p] < m) {
                    bool here = (tv[p - 1] >= m);
                    tv[p] = here ? m : tv[p - 1];
                    ti[p] = here ? a : ti[p - 1];
                }
            }
            if (tv[0] < m) { tv[0] = m; ti[0] = a; }
        }
    }

    // 13 extraction rounds: lists are sorted desc, so the global max of all
    // remaining candidates is some lane's head (slot 0). Butterfly argmax.
    float myv = -3.f; int myi = 0x7fffffff;
    for (int k = 0; k < TOPKN; ++k) {
        float v = tv[0]; int i = ti[0];
#pragma unroll
        for (int s = 1; s < 64; s <<= 1) {
            float vo = __shfl_xor(v, s);
            int   io = __shfl_xor(i, s);
            if (vo > v || (vo == v && io < i)) { v = vo; i = io; }
        }
        if (lane == k) { myv = v; myi = i; }
        bool own = (ti[0] == i);
        // owner shifts its list down one (static indices)
#pragma unroll
        for (int p = 0; p < TOPKN - 1; ++p) {
            tv[p] = own ? tv[p + 1] : tv[p];
            ti[p] = own ? ti[p + 1] : ti[p];
        }
        if (own) { tv[TOPKN - 1] = -3.f; ti[TOPKN - 1] = 0x7fffffff; }
    }
    if (lane < TOPKN) { outv[lane] = myv; outi[lane] = myi; }
}

// ============================================================
// K1b: per row: one wave merges SEG*13 = 208 segment candidates
// into the exact global top-13, applies topk_mask, writes indices.
// ============================================================
__global__ __launch_bounds__(64) void k_topk_merge(
    const float* __restrict__ s1val,
    const int*   __restrict__ s1idx,
    int*         __restrict__ topk_out)   // [1024,13]
{
    const int row  = blockIdx.x;
    const int lane = threadIdx.x;
    const float* __restrict__ v  = s1val + (size_t)row * SEG * TOPKN;
    const int*   __restrict__ ii = s1idx + (size_t)row * SEG * TOPKN;

    float sv[4]; int si[4];
#pragma unroll
    for (int q = 0; q < 4; ++q) {
        int c = lane + 64 * q;
        if (c < SEG * TOPKN) { sv[q] = v[c]; si[q] = ii[c]; }
        else                 { sv[q] = -3.f; si[q] = 0x7fffffff; }
    }

    float myv = -3.f; int myi = 0x7fffffff;
    for (int k = 0; k < TOPKN; ++k) {
        float bv = sv[0]; int bi = si[0];
#pragma unroll
        for (int q = 1; q < 4; ++q) {
            if (sv[q] > bv || (sv[q] == bv && si[q] < bi)) { bv = sv[q]; bi = si[q]; }
        }
#pragma unroll
        for (int s = 1; s < 64; s <<= 1) {
            float vo = __shfl_xor(bv, s);
            int   io = __shfl_xor(bi, s);
            if (vo > bv || (vo == bv && io < bi)) { bv = vo; bi = io; }
        }
        if (lane == k) { myv = bv; myi = bi; }
        // removal (idx unique for live rows; mass-removal of sentinels harmless)
#pragma unroll
        for (int q = 0; q < 4; ++q) {
            if (si[q] == bi && sv[q] == bv) sv[q] = -3.f;
        }
    }
    float w0 = __shfl(myv, 0);            // round-0 winner value = row max
    if (lane < TOPKN)
        topk_out[row * TOPKN + lane] = (w0 > EPSF) ? myi : -1;
}

// ============================================================
// K2: scatter claims (mask_pos before multi-resolution)
// ============================================================
__global__ __launch_bounds__(256) void k_claims(
    const float* __restrict__ anc,
    const float* __restrict__ gt_bboxes,
    const int*   __restrict__ topk,
    int*         __restrict__ counts,
    int*         __restrict__ jsum)
{
    int t = blockIdx.x * 256 + threadIdx.x;
    if (t >= BS * NMAX * TOPKN) return;
    int r = t / TOPKN;
    int a = topk[t];
    if (a < 0) return;
    int b = r >> 6, j = r & 63;
    float gx = gt_bboxes[r * 3 + 0], gy = gt_bboxes[r * 3 + 1], gr = gt_bboxes[r * 3 + 2];
    float dx = gx - anc[a * 2 + 0], dy = gy - anc[a * 2 + 1];
    if (sqrtf(dx * dx + dy * dy) <= gr) {     // mask_in_gts (mask_gt already 1 for live rows)
        atomicAdd(counts + b * NA + a, 1);
        atomicAdd(jsum + b * NA + a, j);
    }
}

// ============================================================
// K3: resolve multi-claim anchors, per-row pos_align/pos_over
// ============================================================
__global__ __launch_bounds__(256) void k_resolve(
    const float* __restrict__ pd_scores,
    const float* __restrict__ pd_circles,
    const float* __restrict__ anc,
    const int*   __restrict__ gt_labels,
    const float* __restrict__ gt_bboxes,
    const float* __restrict__ mask_gt,
    const int*   __restrict__ counts,
    const int*   __restrict__ jsum,
    int*         __restrict__ tgt_ws,
    float*       __restrict__ am_ws,
    unsigned*    __restrict__ pos_align,
    unsigned*    __restrict__ pos_over)
{
    int i = blockIdx.x * 256 + threadIdx.x;   // < BS*NA
    int b = i / NA, a = i - b * NA;
    int cnt = counts[i];
    float ax = anc[a * 2 + 0], ay = anc[a * 2 + 1];

    int tgt = -1;
    if (cnt == 1) {
        tgt = jsum[i];
    } else if (cnt > 1) {
        // argmax_j overlaps[b,j,a]  (masked IoU, first occurrence on ties)
        float px = pd_circles[((size_t)b * NA + a) * 3 + 0];
        float py = pd_circles[((size_t)b * NA + a) * 3 + 1];
        float pr = pd_circles[((size_t)b * NA + a) * 3 + 2];
        float best = -1.f; int bj = 0;
        for (int j = 0; j < NMAX; ++j) {
            int row = b * NMAX + j;
            float ov = 0.f;
            if (mask_gt[row] > 0.f) {
                float gx = gt_bboxes[row * 3 + 0], gy = gt_bboxes[row * 3 + 1], gr = gt_bboxes[row * 3 + 2];
                float dx = gx - ax, dy = gy - ay;
                if (sqrtf(dx * dx + dy * dy) <= gr) {
                    float ddx = gx - px, ddy = gy - py;
                    float d  = sqrtf(ddx * ddx + ddy * ddy);
                    float rs = gr + pr;
                    ov = fmaxf((rs - d) / rs, 0.f);
                }
            }
            if (ov > best) { best = ov; bj = j; }
        }
        tgt = bj;
    }
    tgt_ws[i] = tgt;

    float am = 0.f, ovv = 0.f;
    if (tgt >= 0) {
        int row = b * NMAX + tgt;
        if (mask_gt[row] > 0.f) {
            float gx = gt_bboxes[row * 3 + 0], gy = gt_bboxes[row * 3 + 1], gr = gt_bboxes[row * 3 + 2];
            float dx = gx - ax, dy = gy - ay;
            if (sqrtf(dx * dx + dy * dy) <= gr) {
                float px = pd_circles[((size_t)b * NA + a) * 3 + 0];
                float py = pd_circles[((size_t)b * NA + a) * 3 + 1];
                float pr = pd_circles[((size_t)b * NA + a) * 3 + 2];
                float ddx = gx - px, ddy = gy - py;
                float d  = sqrtf(ddx * ddx + ddy * ddy);
                float rs = gr + pr;
                float iou = fmaxf((rs - d) / rs, 0.f);
                float i2 = iou * iou;
                float s  = pd_scores[((size_t)b * NA + a) * NC + gt_labels[row]];
                am  = s * (i2 * i2 * i2);
                ovv = iou;
            }
        }
        atomicMax(pos_align + row, __float_as_uint(am));
        atomicMax(pos_over  + row, __float_as_uint(ovv));
    }
    am_ws[i] = am;
}

// ============================================================
// K4: write the 5 outputs
// ============================================================
__global__ __launch_bounds__(256) void k_write(
    const int*      __restrict__ gt_labels,
    const float*    __restrict__ gt_bboxes,
    const int*      __restrict__ tgt_ws,
    const float*    __restrict__ am_ws,
    const unsigned* __restrict__ pos_align,
    const unsigned* __restrict__ pos_over,
    float*          __restrict__ out)
{
    int i = blockIdx.x * 256 + threadIdx.x;   // < BS*NA
    int b = i / NA;
    int tgt = tgt_ws[i];
    bool fg = (tgt >= 0);
    int jj  = fg ? tgt : 0;
    int row = b * NMAX + jj;

    int lbl = max(gt_labels[row], 0);
    out[O_LAB + i] = (float)lbl;
    out[O_BOX + (size_t)i * 3 + 0] = gt_bboxes[row * 3 + 0];
    out[O_BOX + (size_t)i * 3 + 1] = gt_bboxes[row * 3 + 1];
    out[O_BOX + (size_t)i * 3 + 2] = gt_bboxes[row * 3 + 2];
    out[O_FG + i] = fg ? 1.f : 0.f;
    out[O_GT + i] = (float)jj;

    if (fg) {
        float pa = __uint_as_float(pos_align[row]);
        float po = __uint_as_float(pos_over[row]);
        float norm = am_ws[i] * po / (pa + EPSF);
        out[O_SCR + (size_t)i * NC + lbl] = norm;
    }
}

// ============================================================
extern "C" void kernel_launch(void* const* d_in, const int* in_sizes, int n_in,
                              void* d_out, int out_size, void* d_ws, size_t ws_size,
                              hipStream_t stream) {
    const float* pd_scores  = (const float*)d_in[0];
    const float* pd_circles = (const float*)d_in[1];
    const float* anc        = (const float*)d_in[2];
    const int*   gt_labels  = (const int*)d_in[3];
    const float* gt_bboxes  = (const float*)d_in[4];
    const float* mask_gt    = (const float*)d_in[5];
    float* out = (float*)d_out;

    char* ws = (char*)d_ws;
    int*      topk      = (int*)(ws + 0);
    float*    s1val     = (float*)(ws + 53248);      // time-shared with counts/jsum
    int*      s1idx     = (int*)(ws + 905216);
    int*      counts    = (int*)(ws + 53248);
    int*      jsum      = (int*)(ws + 2203648);
    int*      tgt_ws    = (int*)(ws + 4354048);
    float*    am_ws     = (float*)(ws + 6504448);
    unsigned* pos_align = (unsigned*)(ws + 8654848);
    unsigned* pos_over  = (unsigned*)(ws + 8658944);

    // big output-scores zeroing first; tiny pos arrays
    hipMemsetAsync(out + O_SCR, 0, (size_t)BS * NA * NC * sizeof(float), stream);
    hipMemsetAsync(pos_align, 0, 2 * 1024 * sizeof(unsigned), stream);

    k_topk_seg<<<BS * NMAX * SEG, 64, 0, stream>>>(pd_scores, pd_circles, anc, gt_labels,
                                                   gt_bboxes, mask_gt, s1val, s1idx);
    k_topk_merge<<<BS * NMAX, 64, 0, stream>>>(s1val, s1idx, topk);

    // counts/jsum share bytes with s1val/s1idx — zero only after the merge
    hipMemsetAsync(counts, 0, 2 * 537600 * sizeof(int), stream);

    k_claims<<<(BS * NMAX * TOPKN + 255) / 256, 256, 0, stream>>>(anc, gt_bboxes, topk,
                                                                  counts, jsum);
    k_resolve<<<(BS * NA) / 256, 256, 0, stream>>>(pd_scores, pd_circles, anc, gt_labels,
                                                   gt_bboxes, mask_gt, counts, jsum,
                                                   tgt_ws, am_ws, pos_align, pos_over);
    k_write<<<(BS * NA) / 256, 256, 0, stream>>>(gt_labels, gt_bboxes, tgt_ws, am_ws,
                                                 pos_align, pos_over, out);
}